// Round 1
// baseline (273.657 us; speedup 1.0000x reference)
//
#include <hip/hip_runtime.h>
#include <math.h>

// Problem: B=16 rows, D=2^21 fp32 per row.
// loss = mean_i( sqrt( sum_j (out[i,j]-lab[i,j])^2 ) )
// Memory-bound streaming reduction: 268 MB read -> floor ~43 us @ 6.3 TB/s.

constexpr int B = 16;
constexpr int D = 2097152;                       // 2^21, divisible by everything below
constexpr int THREADS = 256;
constexpr int VEC_PER_THREAD = 8;                // float4s per thread
constexpr int FLOATS_PER_BLOCK = THREADS * VEC_PER_THREAD * 4;   // 8192
constexpr int BLOCKS_PER_ROW = D / FLOATS_PER_BLOCK;             // 256
constexpr int GRID = B * BLOCKS_PER_ROW;                         // 4096 blocks (~16/CU)

__global__ __launch_bounds__(THREADS)
void sqdiff_partial_kernel(const float4* __restrict__ out,
                           const float4* __restrict__ lab,
                           float* __restrict__ row_sums) {
    const int row   = blockIdx.x / BLOCKS_PER_ROW;
    const int chunk = blockIdx.x % BLOCKS_PER_ROW;
    // base in float4 units; block chunk is contiguous within a row
    const size_t base = (size_t)row * (D / 4)
                      + (size_t)chunk * (THREADS * VEC_PER_THREAD);

    float acc = 0.0f;
#pragma unroll
    for (int i = 0; i < VEC_PER_THREAD; ++i) {
        const size_t idx = base + (size_t)threadIdx.x + (size_t)i * THREADS; // coalesced
        const float4 o = out[idx];
        const float4 l = lab[idx];
        const float dx = o.x - l.x;
        const float dy = o.y - l.y;
        const float dz = o.z - l.z;
        const float dw = o.w - l.w;
        acc = fmaf(dx, dx, acc);
        acc = fmaf(dy, dy, acc);
        acc = fmaf(dz, dz, acc);
        acc = fmaf(dw, dw, acc);
    }

    // wave-64 tree reduce
#pragma unroll
    for (int off = 32; off > 0; off >>= 1)
        acc += __shfl_down(acc, off, 64);

    __shared__ float smem[THREADS / 64];
    const int lane = threadIdx.x & 63;
    const int wave = threadIdx.x >> 6;
    if (lane == 0) smem[wave] = acc;
    __syncthreads();

    if (threadIdx.x == 0) {
        float s = smem[0] + smem[1] + smem[2] + smem[3];
        atomicAdd(&row_sums[row], s);   // 256 atomics per row, device-scope by default
    }
}

__global__ __launch_bounds__(64)
void finalize_kernel(const float* __restrict__ row_sums,
                     float* __restrict__ loss) {
    const int lane = threadIdx.x;
    float v = (lane < B) ? sqrtf(row_sums[lane]) : 0.0f;
#pragma unroll
    for (int off = 32; off > 0; off >>= 1)
        v += __shfl_down(v, off, 64);
    if (lane == 0) loss[0] = v * (1.0f / (float)B);
}

extern "C" void kernel_launch(void* const* d_in, const int* in_sizes, int n_in,
                              void* d_out, int out_size, void* d_ws, size_t ws_size,
                              hipStream_t stream) {
    const float4* out_p = (const float4*)d_in[0];
    const float4* lab_p = (const float4*)d_in[1];
    float* row_sums = (float*)d_ws;          // 16 floats of scratch

    // d_ws is re-poisoned to 0xAA before every timed launch -> must zero it.
    hipMemsetAsync(d_ws, 0, B * sizeof(float), stream);

    sqdiff_partial_kernel<<<GRID, THREADS, 0, stream>>>(out_p, lab_p, row_sums);
    finalize_kernel<<<1, 64, 0, stream>>>(row_sums, (float*)d_out);
}

// Round 2
// 270.972 us; speedup vs baseline: 1.0099x; 1.0099x over previous
//
#include <hip/hip_runtime.h>
#include <math.h>

// Problem: B=16 rows, D=2^21 fp32 per row.
// loss = mean_i( sqrt( sum_j (out[i,j]-lab[i,j])^2 ) )
// R1 finding: atomicAdd from 4096 blocks into one 64B line serialized the
// kernel (~24 ns/atomic, duration invariant to L3 residency). This version
// stores per-block partials (no atomics) + one reduction block.

constexpr int B = 16;
constexpr int D = 2097152;                       // 2^21
constexpr int THREADS = 256;
constexpr int VEC_PER_THREAD = 8;                // float4s per thread
constexpr int FLOATS_PER_BLOCK = THREADS * VEC_PER_THREAD * 4;   // 8192
constexpr int BLOCKS_PER_ROW = D / FLOATS_PER_BLOCK;             // 256
constexpr int GRID = B * BLOCKS_PER_ROW;                         // 4096

__global__ __launch_bounds__(THREADS)
void sqdiff_partial_kernel(const float4* __restrict__ out,
                           const float4* __restrict__ lab,
                           float* __restrict__ partials) {
    const int row   = blockIdx.x / BLOCKS_PER_ROW;
    const int chunk = blockIdx.x % BLOCKS_PER_ROW;
    const size_t base = (size_t)row * (D / 4)
                      + (size_t)chunk * (THREADS * VEC_PER_THREAD);

    float acc = 0.0f;
#pragma unroll
    for (int i = 0; i < VEC_PER_THREAD; ++i) {
        const size_t idx = base + (size_t)threadIdx.x + (size_t)i * THREADS; // coalesced
        const float4 o = out[idx];
        const float4 l = lab[idx];
        const float dx = o.x - l.x;
        const float dy = o.y - l.y;
        const float dz = o.z - l.z;
        const float dw = o.w - l.w;
        acc = fmaf(dx, dx, acc);
        acc = fmaf(dy, dy, acc);
        acc = fmaf(dz, dz, acc);
        acc = fmaf(dw, dw, acc);
    }

    // wave-64 tree reduce
#pragma unroll
    for (int off = 32; off > 0; off >>= 1)
        acc += __shfl_down(acc, off, 64);

    __shared__ float smem[THREADS / 64];
    const int lane = threadIdx.x & 63;
    const int wave = threadIdx.x >> 6;
    if (lane == 0) smem[wave] = acc;
    __syncthreads();

    if (threadIdx.x == 0) {
        // plain store, no atomic: partials laid out [row][chunk] == blockIdx.x
        partials[blockIdx.x] = smem[0] + smem[1] + smem[2] + smem[3];
    }
}

// One block, 1024 threads = 16 waves. Wave w reduces row w's 256 partials.
__global__ __launch_bounds__(1024)
void finalize_kernel(const float* __restrict__ partials,
                     float* __restrict__ loss) {
    const int wave = threadIdx.x >> 6;   // 0..15 == row
    const int lane = threadIdx.x & 63;

    float s = 0.0f;
#pragma unroll
    for (int k = 0; k < BLOCKS_PER_ROW / 64; ++k)        // 4 partials per lane
        s += partials[wave * BLOCKS_PER_ROW + k * 64 + lane];

#pragma unroll
    for (int off = 32; off > 0; off >>= 1)
        s += __shfl_down(s, off, 64);

    __shared__ float row_dist[B];
    if (lane == 0) row_dist[wave] = sqrtf(s);
    __syncthreads();

    if (wave == 0) {
        float v = (lane < B) ? row_dist[lane] : 0.0f;
#pragma unroll
        for (int off = 32; off > 0; off >>= 1)
            v += __shfl_down(v, off, 64);
        if (lane == 0) loss[0] = v * (1.0f / (float)B);
    }
}

extern "C" void kernel_launch(void* const* d_in, const int* in_sizes, int n_in,
                              void* d_out, int out_size, void* d_ws, size_t ws_size,
                              hipStream_t stream) {
    const float4* out_p = (const float4*)d_in[0];
    const float4* lab_p = (const float4*)d_in[1];
    float* partials = (float*)d_ws;          // 4096 floats of scratch, fully overwritten

    sqdiff_partial_kernel<<<GRID, THREADS, 0, stream>>>(out_p, lab_p, partials);
    finalize_kernel<<<1, 1024, 0, stream>>>(partials, (float*)d_out);
}